// Round 6
// baseline (251.235 us; speedup 1.0000x reference)
//
#include <hip/hip_runtime.h>

typedef _Float16 half_t;
typedef _Float16 half8  __attribute__((ext_vector_type(8)));
typedef _Float16 half4v __attribute__((ext_vector_type(4)));
typedef float    f32x16 __attribute__((ext_vector_type(16)));
typedef float    f32x4  __attribute__((ext_vector_type(4)));

#define DEVI static __device__ __forceinline__

constexpr int B_  = 16384;
constexpr int T_  = 28;
constexpr int IN_ = 28;
constexpr int H_  = 128;
constexpr int C_  = 11;
constexpr int BT  = 32;    // batch rows per block; grid = 512 = 2 blocks/CU resident
constexpr int NT  = 256;   // 4 waves = 4 m-tiles x 1 n-tile
constexpr int HSTR = 136;  // LDS stride (halves): 272B rows, 16B-aligned
constexpr int XSTR = 40;   // LDS stride (halves) for x tile: 80B rows, 16B-aligned

// LDS = 52224 + 5120 + 1536 = 58880 B. This EXACT size matters: with NT=256 it
// admits 2 blocks/CU -> backend budgets VGPRs for 2 waves/EU (256) -> no spill
// (R2 evidence: VGPR 184, WRITE 0.7MB). NT=512 (R3/R5) or amdgpu_waves_per_eu
// (R4) both collapse the budget to 128 and spill ~100 regs (WRITE ~51MB).
struct SMem {
  alignas(16) half_t h[3][2][BT * HSTR];  // [layer][buf][b*HSTR+n], double-buffered
  alignas(16) half_t xin[2][BT * XSTR];   // double-buffered x_t tile [b][k]; cols 28..31 = 0
  alignas(16) float  bias[3][H_];         // combined bih+bhh
};

DEVI f32x16 mfma(half8 a, half8 b, f32x16 c) {
  return __builtin_amdgcn_mfma_f32_32x32x16_f16(a, b, c, 0, 0, 0);
}

// A-fragments, one 32-row m-tile of a 128x128 row-major fp32 matrix.
// A layout (32x32x16 f16): lane holds A[m=lane&31][k=(lane>>5)*8+j], j=0..7.
DEVI void loadw(half8 d[8], const float* __restrict__ w, int m, int hf) {
  const float* p = w + m * H_ + hf * 8;
#pragma unroll
  for (int kc = 0; kc < 8; ++kc) {
    half8 f;
#pragma unroll
    for (int j = 0; j < 8; ++j) f[j] = (half_t)p[kc * 16 + j];
    d[kc] = f;
  }
}

// acc(e,o) = Wih . in^T + Whh . hprev^T for this wave's m-tile, 32-batch n-tile.
// Even/odd kc split keeps two independent MFMA chains.
template <int KIN, int ISTR>
DEVI void mmstep(const half_t* __restrict__ inb, const half_t* __restrict__ hp,
                 const half8* awi, const half8* awh,
                 f32x16& e, f32x16& o, int l31, int hf) {
  f32x16 ae = {};
  f32x16 ao = {};
#pragma unroll
  for (int kc = 0; kc < KIN; ++kc) {
    half8 b = *(const half8*)&inb[l31 * ISTR + kc * 16 + hf * 8];
    if (kc & 1) ao = mfma(awi[kc], b, ao);
    else        ae = mfma(awi[kc], b, ae);
  }
#pragma unroll
  for (int kc = 0; kc < 8; ++kc) {
    half8 b = *(const half8*)&hp[l31 * HSTR + kc * 16 + hf * 8];
    if (kc & 1) ao = mfma(awh[kc], b, ao);
    else        ae = mfma(awh[kc], b, ae);
  }
  e = ae;
  o = ao;
}

// h = relu(e + o + bias) -> hout.  C/D layout (HW-verified m74/m101):
// col = lane&31 (batch), row = (reg&3) + 8*(reg>>2) + 4*(lane>>5).
DEVI void epi(half_t* __restrict__ hout, const float* __restrict__ bl,
              f32x16 e, f32x16 o, int mt, int l31, int hf) {
#pragma unroll
  for (int rq = 0; rq < 4; ++rq) {
    const int n0 = mt * 32 + rq * 8 + hf * 4;
    const f32x4 b4 = *(const f32x4*)&bl[n0];   // 2-addr broadcast: cheap
    half4v h4;
#pragma unroll
    for (int ri = 0; ri < 4; ++ri)
      h4[ri] = (half_t)fmaxf(e[rq * 4 + ri] + o[rq * 4 + ri] + b4[ri], 0.0f);
    *(half4v*)&hout[l31 * HSTR + n0] = h4;
  }
}

// Stage x[:, t, :] (32 rows x 28 cols fp32) -> xin buf as fp16. ch<7 covers cols 0..27.
DEVI void stage_x(half_t* __restrict__ xb, const float* __restrict__ x,
                  int b0, int t, int tid) {
  const int row = tid >> 3, ch = tid & 7;
  if (ch < 7) {
    const f32x4 v = *(const f32x4*)(x + (size_t)(b0 + row) * (T_ * IN_) +
                                    (size_t)t * IN_ + ch * 4);
    half4v h4;
#pragma unroll
    for (int j = 0; j < 4; ++j) h4[j] = (half_t)v[j];
    *(half4v*)&xb[row * XSTR + ch * 4] = h4;
  }
}

__global__ __launch_bounds__(NT, 1)
void rnn_fused(const float* __restrict__ x,
               const float* __restrict__ wih0, const float* __restrict__ whh0,
               const float* __restrict__ bih0, const float* __restrict__ bhh0,
               const float* __restrict__ wih1, const float* __restrict__ whh1,
               const float* __restrict__ bih1, const float* __restrict__ bhh1,
               const float* __restrict__ wih2, const float* __restrict__ whh2,
               const float* __restrict__ bih2, const float* __restrict__ bhh2,
               const float* __restrict__ fcw, const float* __restrict__ fcb,
               float* __restrict__ out)
{
  __shared__ SMem sm;
  const int tid  = threadIdx.x;
  const int b0   = blockIdx.x * BT;
  const int lane = tid & 63;
  const int mt   = tid >> 6;       // m-tile: hidden rows [mt*32, +32)
  const int l31  = lane & 31;      // batch row within the 32-row n-tile
  const int hf   = lane >> 5;
  const int m    = mt * 32 + l31;

  // ---- register-resident weights for ALL layers (held across all 28 steps) ----
  half8 ah0[8], ai1[8], ah1[8], ai2[8], ah2[8], ai0[2];
  loadw(ah0, whh0, m, hf);
  loadw(ai1, wih1, m, hf);
  loadw(ah1, whh1, m, hf);
  loadw(ai2, wih2, m, hf);
  loadw(ah2, whh2, m, hf);
#pragma unroll
  for (int kc = 0; kc < 2; ++kc) {   // wih0: K=28 padded to 32 with zeros
    half8 f;
#pragma unroll
    for (int j = 0; j < 8; ++j) {
      const int k = kc * 16 + hf * 8 + j;
      f[j] = (k < IN_) ? (half_t)wih0[m * IN_ + k] : (half_t)0.0f;
    }
    ai0[kc] = f;
  }

  // ---- zero h bufs (buf 0 is h_{-1}=0) and xin (pad cols must be 0) ----
  for (int i = tid; i < (3 * 2 * BT * HSTR + 2 * BT * XSTR) / 2; i += NT)
    ((unsigned int*)sm.h)[i] = 0u;
  if (tid < H_) {
    sm.bias[0][tid] = bih0[tid] + bhh0[tid];
    sm.bias[1][tid] = bih1[tid] + bhh1[tid];
    sm.bias[2][tid] = bih2[tid] + bhh2[tid];
  }
  __syncthreads();
  stage_x(sm.xin[0], x, b0, 0, tid);
  __syncthreads();

  f32x16 e, o;
  for (int t = 0; t < T_; ++t) {
    const int p = t & 1, np = p ^ 1;
    // L0: reads xin[p], h0[p]; writes h0[np] — dbuf, no sync before epi
    mmstep<2, XSTR>(sm.xin[p], sm.h[0][p], ai0, ah0, e, o, l31, hf);
    if (t + 1 < T_) stage_x(sm.xin[np], x, b0, t + 1, tid);  // overlaps epi/mm1
    epi(sm.h[0][np], sm.bias[0], e, o, mt, l31, hf);
    __syncthreads();                       // h0[np] visible
    mmstep<8, HSTR>(sm.h[0][np], sm.h[1][p], ai1, ah1, e, o, l31, hf);
    epi(sm.h[1][np], sm.bias[1], e, o, mt, l31, hf);
    __syncthreads();                       // h1[np] visible
    mmstep<8, HSTR>(sm.h[1][np], sm.h[2][p], ai2, ah2, e, o, l31, hf);
    epi(sm.h[2][np], sm.bias[2], e, o, mt, l31, hf);
    __syncthreads();                       // h2[np] + xin[np] visible for t+1
  }
  // after t=27 (p=1): final h2 in buf 0

  // ---- FC head: out[b][c] = h2_last[b] . fcw[c] + fcb[c] ----
  const int row = tid >> 3, q = tid & 7;
  for (int c = q; c < C_; c += 8) {
    float s = fcb[c];
    const float* wp = fcw + c * H_;
#pragma unroll
    for (int k = 0; k < H_; k += 8) {
      const half8 hv = *(const half8*)&sm.h[2][0][row * HSTR + k];
#pragma unroll
      for (int j = 0; j < 8; ++j) s += (float)hv[j] * wp[k + j];
    }
    out[(size_t)(b0 + row) * C_ + c] = s;
  }
}

extern "C" void kernel_launch(void* const* d_in, const int* in_sizes, int n_in,
                              void* d_out, int out_size, void* d_ws, size_t ws_size,
                              hipStream_t stream)
{
  const float* x    = (const float*)d_in[0];
  const float* wih0 = (const float*)d_in[1];
  const float* whh0 = (const float*)d_in[2];
  const float* bih0 = (const float*)d_in[3];
  const float* bhh0 = (const float*)d_in[4];
  const float* wih1 = (const float*)d_in[5];
  const float* whh1 = (const float*)d_in[6];
  const float* bih1 = (const float*)d_in[7];
  const float* bhh1 = (const float*)d_in[8];
  const float* wih2 = (const float*)d_in[9];
  const float* whh2 = (const float*)d_in[10];
  const float* bih2 = (const float*)d_in[11];
  const float* bhh2 = (const float*)d_in[12];
  const float* fcw  = (const float*)d_in[13];
  const float* fcb  = (const float*)d_in[14];
  float* out = (float*)d_out;

  rnn_fused<<<B_ / BT, NT, 0, stream>>>(x,
      wih0, whh0, bih0, bhh0,
      wih1, whh1, bih1, bhh1,
      wih2, whh2, bih2, bhh2,
      fcw, fcb, out);
}

// Round 7
// 197.567 us; speedup vs baseline: 1.2716x; 1.2716x over previous
//
#include <hip/hip_runtime.h>

typedef _Float16 half_t;
typedef _Float16 half8  __attribute__((ext_vector_type(8)));
typedef _Float16 half4v __attribute__((ext_vector_type(4)));
typedef float    f32x16 __attribute__((ext_vector_type(16)));
typedef float    f32x4  __attribute__((ext_vector_type(4)));

#define DEVI static __device__ __forceinline__

constexpr int B_  = 16384;
constexpr int T_  = 28;
constexpr int IN_ = 28;
constexpr int H_  = 128;
constexpr int C_  = 11;
constexpr int BT  = 64;    // batch rows per block; grid = 256 = 1 block/CU
constexpr int NT  = 512;   // 8 waves: 4x L0, 2x L1, 2x L2 -> 2 waves/SIMD guaranteed
constexpr int HSTR = 136;  // LDS stride (halves): 272B rows, 16B-aligned, conflict-min
constexpr int XSTR = 40;

constexpr int HBUF = BT * HSTR;                 // halves per h buffer
constexpr int XBUF = BT * XSTR;                 // halves per x buffer
constexpr int SM_HALVES = 6 * HBUF + 2 * XBUF;  // h[3][2] + xin[2]
constexpr size_t SM_BYTES = (size_t)SM_HALVES * 2 + 3 * H_ * 4;  // + bias[3][128] f32 = 116224 B

DEVI f32x16 mfma(half8 a, half8 b, f32x16 c) {
  return __builtin_amdgcn_mfma_f32_32x32x16_f16(a, b, c, 0, 0, 0);
}

DEVI half8 frag(const half_t* base, int kc) { return *(const half8*)(base + kc * 16); }

// A-fragments, one 32-row m-tile of a 128x128 row-major fp32 matrix.
// A layout (32x32x16 f16, validated by R2-R6 passing): lane holds A[m=lane&31][k=(lane>>5)*8+j].
DEVI void loadw8(half8 d[8], const float* __restrict__ w, int mrow, int hf) {
  const float* p = w + mrow * H_ + hf * 8;
#pragma unroll
  for (int kc = 0; kc < 8; ++kc) {
    half8 f;
#pragma unroll
    for (int j = 0; j < 8; ++j) f[j] = (half_t)p[kc * 16 + j];
    d[kc] = f;
  }
}

// One C-tile epilogue: h = relu(acc + bias) -> hout[b=ncol0+l31][n=mrow0+...].
// C/D layout (HW-verified m74/m101): col=lane&31, row=(reg&3)+8*(reg>>2)+4*(lane>>5).
DEVI void epi1(half_t* __restrict__ hout, const float* __restrict__ bl,
               f32x16 a, int mrow0, int ncol0, int l31, int hf) {
#pragma unroll
  for (int rq = 0; rq < 4; ++rq) {
    const int n0 = mrow0 + rq * 8 + hf * 4;
    const f32x4 b4 = *(const f32x4*)&bl[n0];
    half4v h4;
#pragma unroll
    for (int ri = 0; ri < 4; ++ri)
      h4[ri] = (half_t)fmaxf(a[rq * 4 + ri] + b4[ri], 0.0f);
    *(half4v*)&hout[(ncol0 + l31) * HSTR + n0] = h4;
  }
}

__global__ __launch_bounds__(NT) __attribute__((amdgpu_waves_per_eu(2)))
void rnn_pipe(const float* __restrict__ x,
              const float* __restrict__ wih0, const float* __restrict__ whh0,
              const float* __restrict__ bih0, const float* __restrict__ bhh0,
              const float* __restrict__ wih1, const float* __restrict__ whh1,
              const float* __restrict__ bih1, const float* __restrict__ bhh1,
              const float* __restrict__ wih2, const float* __restrict__ whh2,
              const float* __restrict__ bih2, const float* __restrict__ bhh2,
              const float* __restrict__ fcw, const float* __restrict__ fcb,
              float* __restrict__ out)
{
  extern __shared__ __align__(16) char smraw[];
  half_t* hs   = (half_t*)smraw;
  float*  bias = (float*)(hs + SM_HALVES);
  // h buffer for (layer l, parity b); x buffer for parity b
#define HB(l, b) (hs + ((l) * 2 + (b)) * HBUF)
#define XB(b)    (hs + 6 * HBUF + (b) * XBUF)

  const int tid  = threadIdx.x;
  const int b0   = blockIdx.x * BT;
  const int lane = tid & 63;
  const int wid  = tid >> 6;
  const int l31  = lane & 31;
  const int hf   = lane >> 5;

  // ---- init: zero all LDS buffers (h_{-1}=0, x pad cols=0), stage biases ----
  for (int i = tid; i < SM_HALVES / 2; i += NT) ((unsigned int*)hs)[i] = 0u;
  if (tid < H_) {
    bias[tid]          = bih0[tid] + bhh0[tid];
    bias[H_ + tid]     = bih1[tid] + bhh1[tid];
    bias[2 * H_ + tid] = bih2[tid] + bhh2[tid];
  }
  __syncthreads();
  {  // stage x[t=0] into XB(0): 64 rows x 7 f32x4 chunks over 448 threads
    const int row = tid >> 3, ch = tid & 7;
    if (ch < 7) {
      const f32x4 v = *(const f32x4*)(x + (size_t)(b0 + row) * (T_ * IN_) + ch * 4);
      half4v h4;
#pragma unroll
      for (int j = 0; j < 4; ++j) h4[j] = (half_t)v[j];
      *(half4v*)&XB(0)[row * XSTR + ch * 4] = h4;
    }
  }
  __syncthreads();

  // ===== wave-specialized pipeline: iter i computes h0[i], h1[i-1], h2[i-2] =====
  // All reads hit parity p buffers, all writes go to parity np: ONE barrier/iter.
  // Barrier counts match across branches (30 each).
  if (wid < 4) {
    // ---- L0: 1 m-tile, both n-tiles; also stages x[t=i+1] ----
    const int mt = wid;
    half8 ai0[2], ah0[8];
    loadw8(ah0, whh0, mt * 32 + l31, hf);
#pragma unroll
    for (int kc = 0; kc < 2; ++kc) {  // wih0: K=28 padded to 32 with zeros
      half8 f;
#pragma unroll
      for (int j = 0; j < 8; ++j) {
        const int k = kc * 16 + hf * 8 + j;
        f[j] = (k < IN_) ? (half_t)wih0[(mt * 32 + l31) * IN_ + k] : (half_t)0.0f;
      }
      ai0[kc] = f;
    }
    const int xrow = tid >> 3, xch = tid & 7;  // tid<256: rows 0..31 (+32 second chunk)
    for (int i = 0; i < T_ + 2; ++i) {
      const int p = i & 1, np = p ^ 1;
      const bool xact = (xch < 7) && (i + 1 < T_);
      f32x4 xq0, xq1;
      if (xact) {  // issue global loads early; consumed at iteration end
        const float* xp = x + (size_t)(i + 1) * IN_ + xch * 4;
        xq0 = *(const f32x4*)(xp + (size_t)(b0 + xrow) * (T_ * IN_));
        xq1 = *(const f32x4*)(xp + (size_t)(b0 + xrow + 32) * (T_ * IN_));
      }
      if (i < T_) {
        const half_t* bx0 = XB(p) + l31 * XSTR + hf * 8;
        const half_t* bx1 = XB(p) + (32 + l31) * XSTR + hf * 8;
        const half_t* bh0 = HB(0, p) + l31 * HSTR + hf * 8;
        const half_t* bh1 = HB(0, p) + (32 + l31) * HSTR + hf * 8;
        f32x16 a0 = {}, a1 = {};
#pragma unroll
        for (int kc = 0; kc < 2; ++kc) {
          a0 = mfma(ai0[kc], frag(bx0, kc), a0);
          a1 = mfma(ai0[kc], frag(bx1, kc), a1);
        }
#pragma unroll
        for (int kc = 0; kc < 8; ++kc) {
          a0 = mfma(ah0[kc], frag(bh0, kc), a0);
          a1 = mfma(ah0[kc], frag(bh1, kc), a1);
        }
        epi1(HB(0, np), bias, a0, mt * 32, 0,  l31, hf);
        epi1(HB(0, np), bias, a1, mt * 32, 32, l31, hf);
      }
      if (xact) {
        half4v h4a, h4b;
#pragma unroll
        for (int j = 0; j < 4; ++j) { h4a[j] = (half_t)xq0[j]; h4b[j] = (half_t)xq1[j]; }
        *(half4v*)&XB(np)[xrow * XSTR + xch * 4] = h4a;
        *(half4v*)&XB(np)[(xrow + 32) * XSTR + xch * 4] = h4b;
      }
      __syncthreads();
    }
  } else if (wid < 6) {
    // ---- L1: 2 m-tiles (B-frag reuse x2), both n-tiles ----
    const int mh = wid - 4;
    half8 wi[2][8], wh[2][8];
    loadw8(wi[0], wih1, (2 * mh) * 32 + l31, hf);
    loadw8(wi[1], wih1, (2 * mh + 1) * 32 + l31, hf);
    loadw8(wh[0], whh1, (2 * mh) * 32 + l31, hf);
    loadw8(wh[1], whh1, (2 * mh + 1) * 32 + l31, hf);
    for (int i = 0; i < T_ + 2; ++i) {
      const int p = i & 1, np = p ^ 1;
      if (i >= 1 && i < T_ + 1) {
        const half_t* bi0 = HB(0, p) + l31 * HSTR + hf * 8;        // input h0[t=i-1]
        const half_t* bi1 = HB(0, p) + (32 + l31) * HSTR + hf * 8;
        const half_t* br0 = HB(1, p) + l31 * HSTR + hf * 8;        // recurrent h1[t=i-2]
        const half_t* br1 = HB(1, p) + (32 + l31) * HSTR + hf * 8;
        f32x16 a00 = {}, a01 = {}, a10 = {}, a11 = {};
#pragma unroll
        for (int kc = 0; kc < 8; ++kc) {
          const half8 b0 = frag(bi0, kc), b1 = frag(bi1, kc);
          a00 = mfma(wi[0][kc], b0, a00);  a01 = mfma(wi[0][kc], b1, a01);
          a10 = mfma(wi[1][kc], b0, a10);  a11 = mfma(wi[1][kc], b1, a11);
        }
#pragma unroll
        for (int kc = 0; kc < 8; ++kc) {
          const half8 b0 = frag(br0, kc), b1 = frag(br1, kc);
          a00 = mfma(wh[0][kc], b0, a00);  a01 = mfma(wh[0][kc], b1, a01);
          a10 = mfma(wh[1][kc], b0, a10);  a11 = mfma(wh[1][kc], b1, a11);
        }
        epi1(HB(1, np), bias + H_, a00, (2 * mh) * 32,     0,  l31, hf);
        epi1(HB(1, np), bias + H_, a01, (2 * mh) * 32,     32, l31, hf);
        epi1(HB(1, np), bias + H_, a10, (2 * mh + 1) * 32, 0,  l31, hf);
        epi1(HB(1, np), bias + H_, a11, (2 * mh + 1) * 32, 32, l31, hf);
      }
      __syncthreads();
    }
  } else {
    // ---- L2: 2 m-tiles, both n-tiles ----
    const int mh = wid - 6;
    half8 wi[2][8], wh[2][8];
    loadw8(wi[0], wih2, (2 * mh) * 32 + l31, hf);
    loadw8(wi[1], wih2, (2 * mh + 1) * 32 + l31, hf);
    loadw8(wh[0], whh2, (2 * mh) * 32 + l31, hf);
    loadw8(wh[1], whh2, (2 * mh + 1) * 32 + l31, hf);
    for (int i = 0; i < T_ + 2; ++i) {
      const int p = i & 1, np = p ^ 1;
      if (i >= 2) {
        const half_t* bi0 = HB(1, p) + l31 * HSTR + hf * 8;        // input h1[t=i-2]
        const half_t* bi1 = HB(1, p) + (32 + l31) * HSTR + hf * 8;
        const half_t* br0 = HB(2, p) + l31 * HSTR + hf * 8;        // recurrent h2[t=i-3]
        const half_t* br1 = HB(2, p) + (32 + l31) * HSTR + hf * 8;
        f32x16 a00 = {}, a01 = {}, a10 = {}, a11 = {};
#pragma unroll
        for (int kc = 0; kc < 8; ++kc) {
          const half8 b0 = frag(bi0, kc), b1 = frag(bi1, kc);
          a00 = mfma(wi[0][kc], b0, a00);  a01 = mfma(wi[0][kc], b1, a01);
          a10 = mfma(wi[1][kc], b0, a10);  a11 = mfma(wi[1][kc], b1, a11);
        }
#pragma unroll
        for (int kc = 0; kc < 8; ++kc) {
          const half8 b0 = frag(br0, kc), b1 = frag(br1, kc);
          a00 = mfma(wh[0][kc], b0, a00);  a01 = mfma(wh[0][kc], b1, a01);
          a10 = mfma(wh[1][kc], b0, a10);  a11 = mfma(wh[1][kc], b1, a11);
        }
        epi1(HB(2, np), bias + 2 * H_, a00, (2 * mh) * 32,     0,  l31, hf);
        epi1(HB(2, np), bias + 2 * H_, a01, (2 * mh) * 32,     32, l31, hf);
        epi1(HB(2, np), bias + 2 * H_, a10, (2 * mh + 1) * 32, 0,  l31, hf);
        epi1(HB(2, np), bias + 2 * H_, a11, (2 * mh + 1) * 32, 32, l31, hf);
      }
      __syncthreads();
    }
  }
  // last in-loop barrier (i=29) makes final h2 (written i=29 -> parity 0) visible

  // ---- FC head: out[b][c] = h2_last[b] . fcw[c] + fcb[c] ----
  const half_t* h2f = HB(2, 0);
  const int row = tid >> 3, q = tid & 7;
  for (int c = q; c < C_; c += 8) {
    float s = fcb[c];
    const float* wp = fcw + c * H_;
#pragma unroll
    for (int k = 0; k < H_; k += 8) {
      const half8 hv = *(const half8*)&h2f[row * HSTR + k];
#pragma unroll
      for (int j = 0; j < 8; ++j) s += (float)hv[j] * wp[k + j];
    }
    out[(size_t)(b0 + row) * C_ + c] = s;
  }
#undef HB
#undef XB
}

extern "C" void kernel_launch(void* const* d_in, const int* in_sizes, int n_in,
                              void* d_out, int out_size, void* d_ws, size_t ws_size,
                              hipStream_t stream)
{
  const float* x    = (const float*)d_in[0];
  const float* wih0 = (const float*)d_in[1];
  const float* whh0 = (const float*)d_in[2];
  const float* bih0 = (const float*)d_in[3];
  const float* bhh0 = (const float*)d_in[4];
  const float* wih1 = (const float*)d_in[5];
  const float* whh1 = (const float*)d_in[6];
  const float* bih1 = (const float*)d_in[7];
  const float* bhh1 = (const float*)d_in[8];
  const float* wih2 = (const float*)d_in[9];
  const float* whh2 = (const float*)d_in[10];
  const float* bih2 = (const float*)d_in[11];
  const float* bhh2 = (const float*)d_in[12];
  const float* fcw  = (const float*)d_in[13];
  const float* fcb  = (const float*)d_in[14];
  float* out = (float*)d_out;

  // 116224 B dynamic LDS > 64 KB default cap: raise the limit (host-side, capture-safe)
  (void)hipFuncSetAttribute((const void*)rnn_pipe,
                            hipFuncAttributeMaxDynamicSharedMemorySize, (int)SM_BYTES);

  rnn_pipe<<<B_ / BT, NT, SM_BYTES, stream>>>(x,
      wih0, whh0, bih0, bhh0,
      wih1, whh1, bih1, bhh1,
      wih2, whh2, bih2, bhh2,
      fcw, fcb, out);
}

// Round 8
// 178.915 us; speedup vs baseline: 1.4042x; 1.1042x over previous
//
#include <hip/hip_runtime.h>

typedef _Float16 half_t;
typedef _Float16 half8  __attribute__((ext_vector_type(8)));
typedef _Float16 half4v __attribute__((ext_vector_type(4)));
typedef float    f32x16 __attribute__((ext_vector_type(16)));
typedef float    f32x4  __attribute__((ext_vector_type(4)));

#define DEVI static __device__ __forceinline__

constexpr int B_  = 16384;
constexpr int T_  = 28;
constexpr int IN_ = 28;
constexpr int H_  = 128;
constexpr int C_  = 11;
constexpr int BT  = 64;    // batch rows per block; grid = 256 = 1 block/CU
constexpr int NT  = 768;   // 12 waves: 4x L0, 4x L1, 4x L2 -> 3 waves/SIMD, one per layer
constexpr int HSTR = 136;  // LDS stride (halves): 272B rows, 16B-aligned, conflict-free b128
constexpr int XSTR = 40;

constexpr int HBUF = BT * HSTR;                 // halves per h buffer
constexpr int XBUF = BT * XSTR;                 // halves per x buffer
constexpr int SM_HALVES = 6 * HBUF + 2 * XBUF;  // h[3][2] + xin[2]
constexpr size_t SM_BYTES = (size_t)SM_HALVES * 2 + 3 * H_ * 4;  // + bias = 116224 B

DEVI f32x16 mfma(half8 a, half8 b, f32x16 c) {
  return __builtin_amdgcn_mfma_f32_32x32x16_f16(a, b, c, 0, 0, 0);
}

DEVI half8 frag(const half_t* base, int kc) { return *(const half8*)(base + kc * 16); }

// A-fragments, one 32-row m-tile of a 128x128 row-major fp32 matrix.
// A layout (32x32x16 f16, validated by R2-R7 passing): lane holds A[m=lane&31][k=(lane>>5)*8+j].
DEVI void loadw8(half8 d[8], const float* __restrict__ w, int mrow, int hf) {
  const float* p = w + mrow * H_ + hf * 8;
#pragma unroll
  for (int kc = 0; kc < 8; ++kc) {
    half8 f;
#pragma unroll
    for (int j = 0; j < 8; ++j) f[j] = (half_t)p[kc * 16 + j];
    d[kc] = f;
  }
}

// One C-tile epilogue: h = relu(acc + bias) -> hout[b=ncol0+l31][n=mrow0+...].
// C/D layout (HW-verified m74/m101): col=lane&31, row=(reg&3)+8*(reg>>2)+4*(lane>>5).
DEVI void epi1(half_t* __restrict__ hout, const float* __restrict__ bl,
               f32x16 a, int mrow0, int ncol0, int l31, int hf) {
#pragma unroll
  for (int rq = 0; rq < 4; ++rq) {
    const int n0 = mrow0 + rq * 8 + hf * 4;
    const f32x4 b4 = *(const f32x4*)&bl[n0];
    half4v h4;
#pragma unroll
    for (int ri = 0; ri < 4; ++ri)
      h4[ri] = (half_t)fmaxf(a[rq * 4 + ri] + b4[ri], 0.0f);
    *(half4v*)&hout[(ncol0 + l31) * HSTR + n0] = h4;
  }
}

// waves_per_eu: min 3 (no max clamp — R4 showed (2,2) is poison). Budget 512/3
// ≈ 170 regs/wave >= ~130 demand -> headroom, no spill, no AGPR shuffle.
__global__ __launch_bounds__(NT) __attribute__((amdgpu_waves_per_eu(3)))
void rnn_pipe(const float* __restrict__ x,
              const float* __restrict__ wih0, const float* __restrict__ whh0,
              const float* __restrict__ bih0, const float* __restrict__ bhh0,
              const float* __restrict__ wih1, const float* __restrict__ whh1,
              const float* __restrict__ bih1, const float* __restrict__ bhh1,
              const float* __restrict__ wih2, const float* __restrict__ whh2,
              const float* __restrict__ bih2, const float* __restrict__ bhh2,
              const float* __restrict__ fcw, const float* __restrict__ fcb,
              float* __restrict__ out)
{
  extern __shared__ __align__(16) char smraw[];
  half_t* hs   = (half_t*)smraw;
  float*  bias = (float*)(hs + SM_HALVES);
#define HB(l, b) (hs + ((l) * 2 + (b)) * HBUF)
#define XB(b)    (hs + 6 * HBUF + (b) * XBUF)

  const int tid  = threadIdx.x;
  const int b0   = blockIdx.x * BT;
  const int lane = tid & 63;
  const int wid  = tid >> 6;
  const int l31  = lane & 31;
  const int hf   = lane >> 5;

  // ---- init: zero all LDS buffers (h_{-1}=0, x pad cols=0), stage biases ----
  for (int i = tid; i < SM_HALVES / 2; i += NT) ((unsigned int*)hs)[i] = 0u;
  if (tid < H_) {
    bias[tid]          = bih0[tid] + bhh0[tid];
    bias[H_ + tid]     = bih1[tid] + bhh1[tid];
    bias[2 * H_ + tid] = bih2[tid] + bhh2[tid];
  }
  __syncthreads();
  if (tid < 512) {  // stage x[t=0] into XB(0): 64 rows x 7 f32x4 chunks
    const int row = tid >> 3, ch = tid & 7;
    if (ch < 7) {
      const f32x4 v = *(const f32x4*)(x + (size_t)(b0 + row) * (T_ * IN_) + ch * 4);
      half4v h4;
#pragma unroll
      for (int j = 0; j < 4; ++j) h4[j] = (half_t)v[j];
      *(half4v*)&XB(0)[row * XSTR + ch * 4] = h4;
    }
  }
  __syncthreads();

  // ===== wave-specialized pipeline: iter i computes h0[i], h1[i-1], h2[i-2] =====
  // Reads hit parity p, writes parity np: ONE barrier/iter; 30 barriers per branch.
  if (wid < 4) {
    // ---- L0: 1 m-tile, 2 n-tiles; also stages x[t=i+1] (tids 0..255) ----
    const int mt = wid;
    half8 ai0[2], ah0[8];
    loadw8(ah0, whh0, mt * 32 + l31, hf);
#pragma unroll
    for (int kc = 0; kc < 2; ++kc) {  // wih0: K=28 padded to 32 with zeros
      half8 f;
#pragma unroll
      for (int j = 0; j < 8; ++j) {
        const int k = kc * 16 + hf * 8 + j;
        f[j] = (k < IN_) ? (half_t)wih0[(mt * 32 + l31) * IN_ + k] : (half_t)0.0f;
      }
      ai0[kc] = f;
    }
    const int xrow = tid >> 3, xch = tid & 7;  // tid<256: rows 0..31 (+32 second chunk)
    for (int i = 0; i < T_ + 2; ++i) {
      const int p = i & 1, np = p ^ 1;
      const bool xact = (xch < 7) && (i + 1 < T_);
      f32x4 xq0, xq1;
      if (xact) {  // issue global loads early; consumed at iteration end
        const float* xp = x + (size_t)(i + 1) * IN_ + xch * 4;
        xq0 = *(const f32x4*)(xp + (size_t)(b0 + xrow) * (T_ * IN_));
        xq1 = *(const f32x4*)(xp + (size_t)(b0 + xrow + 32) * (T_ * IN_));
      }
      if (i < T_) {
        const half_t* bx0 = XB(p) + l31 * XSTR + hf * 8;
        const half_t* bx1 = XB(p) + (32 + l31) * XSTR + hf * 8;
        const half_t* bh0 = HB(0, p) + l31 * HSTR + hf * 8;
        const half_t* bh1 = HB(0, p) + (32 + l31) * HSTR + hf * 8;
        f32x16 a0 = {}, a1 = {};
#pragma unroll
        for (int kc = 0; kc < 2; ++kc) {
          a0 = mfma(ai0[kc], frag(bx0, kc), a0);
          a1 = mfma(ai0[kc], frag(bx1, kc), a1);
        }
#pragma unroll
        for (int kc = 0; kc < 8; ++kc) {
          a0 = mfma(ah0[kc], frag(bh0, kc), a0);
          a1 = mfma(ah0[kc], frag(bh1, kc), a1);
        }
        epi1(HB(0, np), bias, a0, mt * 32, 0,  l31, hf);
        epi1(HB(0, np), bias, a1, mt * 32, 32, l31, hf);
      }
      if (xact) {
        half4v h4a, h4b;
#pragma unroll
        for (int j = 0; j < 4; ++j) { h4a[j] = (half_t)xq0[j]; h4b[j] = (half_t)xq1[j]; }
        *(half4v*)&XB(np)[xrow * XSTR + xch * 4] = h4a;
        *(half4v*)&XB(np)[(xrow + 32) * XSTR + xch * 4] = h4b;
      }
      __syncthreads();
    }
  } else if (wid < 8) {
    // ---- L1: 1 m-tile, 2 n-tiles ----
    const int mt1 = wid - 4;
    half8 wi[8], wh[8];
    loadw8(wi, wih1, mt1 * 32 + l31, hf);
    loadw8(wh, whh1, mt1 * 32 + l31, hf);
    for (int i = 0; i < T_ + 2; ++i) {
      const int p = i & 1, np = p ^ 1;
      if (i >= 1 && i < T_ + 1) {
        const half_t* bi0 = HB(0, p) + l31 * HSTR + hf * 8;        // input h0[t=i-1]
        const half_t* bi1 = HB(0, p) + (32 + l31) * HSTR + hf * 8;
        const half_t* br0 = HB(1, p) + l31 * HSTR + hf * 8;        // recurrent h1[t=i-2]
        const half_t* br1 = HB(1, p) + (32 + l31) * HSTR + hf * 8;
        f32x16 a0 = {}, a1 = {};
#pragma unroll
        for (int kc = 0; kc < 8; ++kc) {
          a0 = mfma(wi[kc], frag(bi0, kc), a0);
          a1 = mfma(wi[kc], frag(bi1, kc), a1);
        }
#pragma unroll
        for (int kc = 0; kc < 8; ++kc) {
          a0 = mfma(wh[kc], frag(br0, kc), a0);
          a1 = mfma(wh[kc], frag(br1, kc), a1);
        }
        epi1(HB(1, np), bias + H_, a0, mt1 * 32, 0,  l31, hf);
        epi1(HB(1, np), bias + H_, a1, mt1 * 32, 32, l31, hf);
      }
      __syncthreads();
    }
  } else {
    // ---- L2: 1 m-tile, 2 n-tiles ----
    const int mt2 = wid - 8;
    half8 wi[8], wh[8];
    loadw8(wi, wih2, mt2 * 32 + l31, hf);
    loadw8(wh, whh2, mt2 * 32 + l31, hf);
    for (int i = 0; i < T_ + 2; ++i) {
      const int p = i & 1, np = p ^ 1;
      if (i >= 2) {
        const half_t* bi0 = HB(1, p) + l31 * HSTR + hf * 8;        // input h1[t=i-2]
        const half_t* bi1 = HB(1, p) + (32 + l31) * HSTR + hf * 8;
        const half_t* br0 = HB(2, p) + l31 * HSTR + hf * 8;        // recurrent h2[t=i-3]
        const half_t* br1 = HB(2, p) + (32 + l31) * HSTR + hf * 8;
        f32x16 a0 = {}, a1 = {};
#pragma unroll
        for (int kc = 0; kc < 8; ++kc) {
          a0 = mfma(wi[kc], frag(bi0, kc), a0);
          a1 = mfma(wi[kc], frag(bi1, kc), a1);
        }
#pragma unroll
        for (int kc = 0; kc < 8; ++kc) {
          a0 = mfma(wh[kc], frag(br0, kc), a0);
          a1 = mfma(wh[kc], frag(br1, kc), a1);
        }
        epi1(HB(2, np), bias + 2 * H_, a0, mt2 * 32, 0,  l31, hf);
        epi1(HB(2, np), bias + 2 * H_, a1, mt2 * 32, 32, l31, hf);
      }
      __syncthreads();
    }
  }
  // last in-loop barrier (i=29) makes final h2 (parity 0) visible

  // ---- FC head: out[b][c] = h2_last[b] . fcw[c] + fcb[c] ----
  if (tid < 512) {
    const half_t* h2f = HB(2, 0);
    const int row = tid >> 3, q = tid & 7;
    for (int c = q; c < C_; c += 8) {
      float s = fcb[c];
      const float* wp = fcw + c * H_;
#pragma unroll
      for (int k = 0; k < H_; k += 8) {
        const half8 hv = *(const half8*)&h2f[row * HSTR + k];
#pragma unroll
        for (int j = 0; j < 8; ++j) s += (float)hv[j] * wp[k + j];
      }
      out[(size_t)(b0 + row) * C_ + c] = s;
    }
  }
#undef HB
#undef XB
}

extern "C" void kernel_launch(void* const* d_in, const int* in_sizes, int n_in,
                              void* d_out, int out_size, void* d_ws, size_t ws_size,
                              hipStream_t stream)
{
  const float* x    = (const float*)d_in[0];
  const float* wih0 = (const float*)d_in[1];
  const float* whh0 = (const float*)d_in[2];
  const float* bih0 = (const float*)d_in[3];
  const float* bhh0 = (const float*)d_in[4];
  const float* wih1 = (const float*)d_in[5];
  const float* whh1 = (const float*)d_in[6];
  const float* bih1 = (const float*)d_in[7];
  const float* bhh1 = (const float*)d_in[8];
  const float* wih2 = (const float*)d_in[9];
  const float* whh2 = (const float*)d_in[10];
  const float* bih2 = (const float*)d_in[11];
  const float* bhh2 = (const float*)d_in[12];
  const float* fcw  = (const float*)d_in[13];
  const float* fcb  = (const float*)d_in[14];
  float* out = (float*)d_out;

  (void)hipFuncSetAttribute((const void*)rnn_pipe,
                            hipFuncAttributeMaxDynamicSharedMemorySize, (int)SM_BYTES);

  rnn_pipe<<<B_ / BT, NT, SM_BYTES, stream>>>(x,
      wih0, whh0, bih0, bhh0,
      wih1, whh1, bih1, bhh1,
      wih2, whh2, bih2, bhh2,
      fcw, fcb, out);
}